// Round 3
// baseline (760.742 us; speedup 1.0000x reference)
//
#include <hip/hip_runtime.h>
#include <cstdint>
#include <cstddef>
#include <cstring>

// Problem dims (RNN_57208964382771)
#define Bz 64
#define Tz 2048
#define Hz 8
#define Vz 1000
#define Oz 1000

// 2/ln2 — folded into W_hh and x_proj so fast_tanh skips its input scaling mul
#define SCALE 2.885390081777927f
// xp clamp: 126 - 8*0.354*SCALE (max |h|-contribution) ~= 117.8 -> 117
#define XPCLAMP 117.0f

typedef float f32x4 __attribute__((ext_vector_type(4)));

// ---------------------------------------------------------------------------
// Kernel 1: xpT[b][q][t][e] = min((dot(emb[X[b,t]], W_ih[2q+e,:]) + b_ih +
//           b_hh) * SCALE, XPCLAMP)
// Lane-major layout so the scan's per-lane reads are contiguous over t.
// Also writes the lengths tail of d_out and zeroes the progress flags
// (stream order + kernel-boundary writeback makes prog=0 visible to k_fused).
// ---------------------------------------------------------------------------
__global__ __launch_bounds__(256) void k_xproj(
    const int* __restrict__ X, const int* __restrict__ lengths,
    const float* __restrict__ emb, const float* __restrict__ W_ih,
    const float* __restrict__ b_ih, const float* __restrict__ b_hh,
    float* __restrict__ xpT, float* __restrict__ out_tail,
    int* __restrict__ prog)
{
    int r = blockIdx.x * 256 + threadIdx.x;
    if (r < Bz * Tz) {
        int v = X[r];
        const float4* e4 = (const float4*)(emb + (size_t)v * Hz);
        float4 ea = e4[0], eb = e4[1];
        float res[8];
#pragma unroll
        for (int i = 0; i < 8; ++i) {
            const float* w = W_ih + i * 8;  // uniform address -> scalar loads
            float a = b_ih[i] + b_hh[i];
            a = fmaf(ea.x, w[0], a); a = fmaf(ea.y, w[1], a);
            a = fmaf(ea.z, w[2], a); a = fmaf(ea.w, w[3], a);
            a = fmaf(eb.x, w[4], a); a = fmaf(eb.y, w[5], a);
            a = fmaf(eb.z, w[6], a); a = fmaf(eb.w, w[7], a);
            res[i] = fminf(a * SCALE, XPCLAMP);  // upper clamp off the scan path
        }
        int b = r >> 11, t = r & 2047;
#pragma unroll
        for (int q = 0; q < 4; ++q) {
            *(float2*)(xpT + ((size_t)(b * 4 + q) * Tz + t) * 2) =
                make_float2(res[2 * q], res[2 * q + 1]);
        }
    }
    if (r < Bz) out_tail[r] = (float)lengths[r];
    if (prog != nullptr && r < 8) prog[r] = 0;
}

// ---------------------------------------------------------------------------
// Scan core: h = tanh(xp_t + W_hh h), 4 lanes/batch, lane q holds h[2q],h[2q+1].
// Cross-lane h all-gather via DPP quad_perm. Dot tree-reduced (~16cy chain).
// hs is T-MAJOR hs[t][b][8]: 512 contiguous B per wave per step.
// PUB=true: stores are relaxed agent-scope (write-through to L3, device
// visible); every 256 steps publish prog[wv] after an inline s_waitcnt
// vmcnt(0) (data acked into L3 strictly before the flag store issues).
// ---------------------------------------------------------------------------
#define QROT(x, CTRL) \
    __int_as_float(__builtin_amdgcn_update_dpp(0, __float_as_int(x), (CTRL), 0xF, 0xF, true))
// quad_perm ctrl: rot1=[1,2,3,0]=0x39, rot2=[2,3,0,1]=0x4E, rot3=[3,0,1,2]=0x93

__device__ __forceinline__ float fast_tanh_pre(float m) {
    // m = 2*a/ln2 already; bounded < 126 by the xproj clamp (+h headroom).
    // tanh(a) = (e-1)/(e+1), e = 2^m; exp2(-big)->0 gives -1 exactly.
#if __has_builtin(__builtin_amdgcn_exp2f)
    float e = __builtin_amdgcn_exp2f(m);
#else
    float e = exp2f(m);
#endif
#if __has_builtin(__builtin_amdgcn_rcpf)
    return (e - 1.0f) * __builtin_amdgcn_rcpf(e + 1.0f);
#else
    return (e - 1.0f) / (e + 1.0f);
#endif
}

#define STEP(xx, yy, toff) do { \
    float p1x = QROT(h0, 0x39), p1y = QROT(h1, 0x39); \
    float p2x = QROT(h0, 0x4E), p2y = QROT(h1, 0x4E); \
    float p3x = QROT(h0, 0x93), p3y = QROT(h1, 0x93); \
    float s0a = fmaf(h1, w0[1], fmaf(h0, w0[0], (xx))); \
    float s0b = fmaf(h1, w1[1], fmaf(h0, w1[0], (yy))); \
    float s1a = fmaf(p1y, w0[3], p1x * w0[2]); \
    float s1b = fmaf(p1y, w1[3], p1x * w1[2]); \
    float s2a = fmaf(p2y, w0[5], p2x * w0[4]); \
    float s2b = fmaf(p2y, w1[5], p2x * w1[4]); \
    float s3a = fmaf(p3y, w0[7], p3x * w0[6]); \
    float s3b = fmaf(p3y, w1[7], p3x * w1[6]); \
    h0 = fast_tanh_pre((s0a + s1a) + (s2a + s3a)); \
    h1 = fast_tanh_pre((s0b + s1b) + (s2b + s3b)); \
    if (PUB) { \
        float2 hv = make_float2(h0, h1); uint64_t uu; \
        __builtin_memcpy(&uu, &hv, 8); \
        __hip_atomic_store( \
            (uint64_t*)(hs_base + (size_t)(toff) * (Bz * Hz)), uu, \
            __ATOMIC_RELAXED, __HIP_MEMORY_SCOPE_AGENT); \
    } else { \
        *(float2*)(hs_base + (size_t)(toff) * (Bz * Hz)) = make_float2(h0, h1); \
    } \
} while (0)

template <bool PUB>
__device__ __forceinline__ void scan_run(
    const float* __restrict__ xpT, const float* __restrict__ W_hh,
    float* __restrict__ hs, int b, int q, int* prog, int wv)
{
    int i0 = 2 * q, i1 = 2 * q + 1;
    // Weights in quad-rotation order: term r uses h-pair from lane (q+r)&3.
    float w0[8], w1[8];
#pragma unroll
    for (int r = 0; r < 4; ++r) {
        int jj = ((q + r) & 3) * 2;
        w0[2 * r]     = W_hh[i0 * 8 + jj]     * SCALE;
        w0[2 * r + 1] = W_hh[i0 * 8 + jj + 1] * SCALE;
        w1[2 * r]     = W_hh[i1 * 8 + jj]     * SCALE;
        w1[2 * r + 1] = W_hh[i1 * 8 + jj + 1] * SCALE;
    }

    const float4* xp4 = (const float4*)(xpT + (size_t)(b * 4 + q) * Tz * 2);
    float* hs_base = hs + (size_t)b * Hz + 2 * q;   // t-major: + t*(Bz*Hz)

    float h0 = 0.0f, h1 = 0.0f;
    // prefetch depth 2 (cover ~500cy L3 latency; 8 steps ~ 500cy compute)
    float4 A0 = xp4[0], A1 = xp4[1], A2 = xp4[2], A3 = xp4[3];
    float4 B0 = xp4[4], B1 = xp4[5], B2 = xp4[6], B3 = xp4[7];

    for (int c = 0; c < Tz / 8; ++c) {
        // reads up to 128B past the lane stream on the last iters -> lands in
        // the next lane's stream / start of hs region. Allocated; harmless.
        float4 C0 = xp4[4 * c + 8],  C1 = xp4[4 * c + 9];
        float4 C2 = xp4[4 * c + 10], C3 = xp4[4 * c + 11];
        int t0 = c * 8;
        STEP(A0.x, A0.y, t0 + 0); STEP(A0.z, A0.w, t0 + 1);
        STEP(A1.x, A1.y, t0 + 2); STEP(A1.z, A1.w, t0 + 3);
        STEP(A2.x, A2.y, t0 + 4); STEP(A2.z, A2.w, t0 + 5);
        STEP(A3.x, A3.y, t0 + 6); STEP(A3.z, A3.w, t0 + 7);
        A0 = B0; A1 = B1; A2 = B2; A3 = B3;
        B0 = C0; B1 = C1; B2 = C2; B3 = C3;
        if (PUB && ((c & 31) == 31)) {
            // drain this wave's write-through hs stores into L3, then flag
            asm volatile("s_waitcnt vmcnt(0)" ::: "memory");
            if ((threadIdx.x & 63) == 0)
                __hip_atomic_store(&prog[wv], (c >> 5) + 1,
                                   __ATOMIC_RELAXED, __HIP_MEMORY_SCOPE_AGENT);
        }
    }
}

// Fallback standalone scan (plain stores; kernel boundary is the release).
__global__ __launch_bounds__(64) void k_scan(
    const float* __restrict__ xpT, const float* __restrict__ W_hh,
    float* __restrict__ hs)
{
    int lane = threadIdx.x;
    scan_run<false>(xpT, W_hh, hs, blockIdx.x * 16 + (lane >> 2), lane & 3,
                    nullptr, 0);
}

// ---------------------------------------------------------------------------
// Fused producer/consumer kernel. 256 blocks (<= #CUs -> all co-resident).
// Block 0: 4 scan waves (16 batches each), publish prog[wv] per 256-step chunk.
// Blocks 1..255: tile = one t-value x 64 batches (2KB contiguous hs stage,
// 256KB logits store). Block k handles t = k-1, k-1+255, ... so each chunk's
// 256 tiles land on all 255 blocks -> chunk drain (~10us at full BW) matches
// chunk production cadence. hs/flag reads are agent-scope (bypass stale L2).
// ---------------------------------------------------------------------------
__global__ __launch_bounds__(256) void k_fused(
    const float* __restrict__ xpT, const float* __restrict__ W_hh,
    float* __restrict__ hs, const int* __restrict__ lengths,
    const float* __restrict__ W_out, const float* __restrict__ b_out,
    float* __restrict__ out, int* __restrict__ prog)
{
    __shared__ float4 sh4[128];  // 64 rows x 8 floats
    int tid = threadIdx.x;

    if (blockIdx.x == 0) {  // producer
        __builtin_amdgcn_s_setprio(3);  // win issue ties if a consumer co-resides
        int lane = tid & 63, wv = tid >> 6;
        scan_run<true>(xpT, W_hh, hs, wv * 16 + (lane >> 2), lane & 3, prog, wv);
        return;
    }

    // consumer: hoist W_out rows + bias into registers
    float w[4][8], bo[4];
    if (tid < Oz / 4) {
#pragma unroll
        for (int k = 0; k < 4; ++k) {
            const float4* wr = (const float4*)(W_out + (size_t)(tid * 4 + k) * 8);
            float4 wa = wr[0], wb = wr[1];
            w[k][0] = wa.x; w[k][1] = wa.y; w[k][2] = wa.z; w[k][3] = wa.w;
            w[k][4] = wb.x; w[k][5] = wb.y; w[k][6] = wb.z; w[k][7] = wb.w;
            bo[k] = b_out[tid * 4 + k];
        }
    }

    for (int t = (int)blockIdx.x - 1; t < Tz; t += 255) {
        int need = (t >> 8) + 1;  // chunk index + 1
        if (tid == 0) {
            for (;;) {
                int m0 = __hip_atomic_load(&prog[0], __ATOMIC_RELAXED,
                                           __HIP_MEMORY_SCOPE_AGENT);
                int m1 = __hip_atomic_load(&prog[1], __ATOMIC_RELAXED,
                                           __HIP_MEMORY_SCOPE_AGENT);
                int m2 = __hip_atomic_load(&prog[2], __ATOMIC_RELAXED,
                                           __HIP_MEMORY_SCOPE_AGENT);
                int m3 = __hip_atomic_load(&prog[3], __ATOMIC_RELAXED,
                                           __HIP_MEMORY_SCOPE_AGENT);
                int mn = min(min(m0, m1), min(m2, m3));
                if (mn >= need) break;
                __builtin_amdgcn_s_sleep(4);
            }
        }
        __syncthreads();  // flag observed; barrier orders the hs loads below

        {   // stage 2KB contiguous: 256 threads x 8B (agent loads: L3-fresh)
            uint64_t u = __hip_atomic_load(
                (const uint64_t*)hs + (size_t)t * 256 + tid,
                __ATOMIC_RELAXED, __HIP_MEMORY_SCOPE_AGENT);
            float2 v;
            __builtin_memcpy(&v, &u, 8);
            int b = tid >> 2;  // 4 threads per batch row
            if (t >= lengths[b]) v = make_float2(0.f, 0.f);
            ((float2*)sh4)[tid] = v;
        }
        __syncthreads();

        if (tid < Oz / 4) {  // 250 active threads
            for (int rr = 0; rr < 64; ++rr) {  // rr = batch
                float4 ha = sh4[rr * 2], hb = sh4[rr * 2 + 1];  // LDS broadcast
                float r[4];
#pragma unroll
                for (int k = 0; k < 4; ++k) {
                    float a = bo[k];
                    a = fmaf(ha.x, w[k][0], a); a = fmaf(ha.y, w[k][1], a);
                    a = fmaf(ha.z, w[k][2], a); a = fmaf(ha.w, w[k][3], a);
                    a = fmaf(hb.x, w[k][4], a); a = fmaf(hb.y, w[k][5], a);
                    a = fmaf(hb.z, w[k][6], a); a = fmaf(hb.w, w[k][7], a);
                    r[k] = a;
                }
                f32x4 acc = { r[0], r[1], r[2], r[3] };
                // plain (cached) store: full-line streaming through L2
                *((f32x4*)(out + ((size_t)rr * Tz + t) * Oz) + tid) = acc;
            }
        }
        __syncthreads();  // LDS reused next tile
    }
}

// ---------------------------------------------------------------------------
// Fallback output projection (3-kernel path), t-major hs, 2t x 64b tiles.
// ---------------------------------------------------------------------------
__global__ __launch_bounds__(256) void k_out(
    const float* __restrict__ hs, const int* __restrict__ lengths,
    const float* __restrict__ W_out, const float* __restrict__ b_out,
    float* __restrict__ out)
{
    __shared__ float4 sh4[256];  // 128 rows x 8 floats; row rr = tt*64 + b
    int tid = threadIdx.x;
    int t0 = blockIdx.x * 2;

    {
        float4 v = ((const float4*)hs)[(size_t)t0 * 128 + tid];
        int tt = tid >> 7, b = (tid & 127) >> 1;
        if (t0 + tt >= lengths[b]) v = make_float4(0.f, 0.f, 0.f, 0.f);
        sh4[tid] = v;
    }
    __syncthreads();

    if (tid >= Oz / 4) return;

    float w[4][8];
    float bo[4];
#pragma unroll
    for (int k = 0; k < 4; ++k) {
        const float4* wr = (const float4*)(W_out + (size_t)(tid * 4 + k) * 8);
        float4 wa = wr[0], wb = wr[1];
        w[k][0] = wa.x; w[k][1] = wa.y; w[k][2] = wa.z; w[k][3] = wa.w;
        w[k][4] = wb.x; w[k][5] = wb.y; w[k][6] = wb.z; w[k][7] = wb.w;
        bo[k] = b_out[tid * 4 + k];
    }

    for (int rr = 0; rr < 128; ++rr) {
        float4 ha = sh4[rr * 2], hb = sh4[rr * 2 + 1];
        int tt = rr >> 6, b = rr & 63;
        float r[4];
#pragma unroll
        for (int k = 0; k < 4; ++k) {
            float a = bo[k];
            a = fmaf(ha.x, w[k][0], a); a = fmaf(ha.y, w[k][1], a);
            a = fmaf(ha.z, w[k][2], a); a = fmaf(ha.w, w[k][3], a);
            a = fmaf(hb.x, w[k][4], a); a = fmaf(hb.y, w[k][5], a);
            a = fmaf(hb.z, w[k][6], a); a = fmaf(hb.w, w[k][7], a);
            r[k] = a;
        }
        f32x4 acc = { r[0], r[1], r[2], r[3] };
        *((f32x4*)(out + ((size_t)b * Tz + t0 + tt) * Oz) + tid) = acc;
    }
}

// ---------------------------------------------------------------------------
extern "C" void kernel_launch(void* const* d_in, const int* in_sizes, int n_in,
                              void* d_out, int out_size, void* d_ws, size_t ws_size,
                              hipStream_t stream)
{
    const int*   X       = (const int*)d_in[0];
    const int*   lengths = (const int*)d_in[1];
    const float* emb     = (const float*)d_in[2];
    const float* W_ih    = (const float*)d_in[3];
    const float* W_hh    = (const float*)d_in[4];
    const float* b_ih    = (const float*)d_in[5];
    const float* b_hh    = (const float*)d_in[6];
    const float* W_out   = (const float*)d_in[7];
    const float* b_out   = (const float*)d_in[8];

    float* out   = (float*)d_out;
    float* xpT   = (float*)d_ws;                     // 4 MB (lane-major x_proj)
    float* hs    = xpT + (size_t)Bz * Tz * Hz;       // 4 MB (t-major hidden states)

    // lengths tail of d_out (output 1 of the tuple)
    float* out_tail = out + (size_t)Bz * Tz * Oz;

    size_t base = (size_t)Bz * Tz * Hz * 4 * 2;      // 8 MB (xpT + hs)
    bool fused = (ws_size >= base + 64);
    int* prog = fused ? (int*)((char*)d_ws + base) : nullptr;

    k_xproj<<<(Bz * Tz + 255) / 256, 256, 0, stream>>>(X, lengths, emb, W_ih,
                                                       b_ih, b_hh, xpT, out_tail,
                                                       prog);
    if (fused) {
        k_fused<<<256, 256, 0, stream>>>(xpT, W_hh, hs, lengths, W_out, b_out,
                                         out, prog);
    } else {
        k_scan<<<Bz / 16, 64, 0, stream>>>(xpT, W_hh, hs);
        k_out<<<Tz / 2, 256, 0, stream>>>(hs, lengths, W_out, b_out, out);
    }
}

// Round 4
// 741.236 us; speedup vs baseline: 1.0263x; 1.0263x over previous
//
#include <hip/hip_runtime.h>
#include <cstdint>
#include <cstddef>
#include <cstring>

// Problem dims (RNN_57208964382771)
#define Bz 64
#define Tz 2048
#define Hz 8
#define Vz 1000
#define Oz 1000

// 2/ln2 — folded into W_hh and x_proj so fast_tanh skips its input scaling mul
#define SCALE 2.885390081777927f
// xp clamp: 126 - 8*0.354*SCALE (max |h|-contribution) ~= 117.8 -> 117
#define XPCLAMP 117.0f

typedef float f32x4 __attribute__((ext_vector_type(4)));

// ---------------------------------------------------------------------------
// Kernel 1: xpT[b][q][t][e] = min((dot(emb[X[b,t]], W_ih[2q+e,:]) + b_ih +
//           b_hh) * SCALE, XPCLAMP)
// Lane-major layout so the scan's per-lane reads are contiguous over t.
// Also writes the lengths tail of d_out and zeroes the (padded) progress
// flags (stream order + kernel-boundary writeback makes them visible).
// ---------------------------------------------------------------------------
__global__ __launch_bounds__(256) void k_xproj(
    const int* __restrict__ X, const int* __restrict__ lengths,
    const float* __restrict__ emb, const float* __restrict__ W_ih,
    const float* __restrict__ b_ih, const float* __restrict__ b_hh,
    float* __restrict__ xpT, float* __restrict__ out_tail,
    int* __restrict__ prog)
{
    int r = blockIdx.x * 256 + threadIdx.x;
    if (r < Bz * Tz) {
        int v = X[r];
        const float4* e4 = (const float4*)(emb + (size_t)v * Hz);
        float4 ea = e4[0], eb = e4[1];
        float res[8];
#pragma unroll
        for (int i = 0; i < 8; ++i) {
            const float* w = W_ih + i * 8;  // uniform address -> scalar loads
            float a = b_ih[i] + b_hh[i];
            a = fmaf(ea.x, w[0], a); a = fmaf(ea.y, w[1], a);
            a = fmaf(ea.z, w[2], a); a = fmaf(ea.w, w[3], a);
            a = fmaf(eb.x, w[4], a); a = fmaf(eb.y, w[5], a);
            a = fmaf(eb.z, w[6], a); a = fmaf(eb.w, w[7], a);
            res[i] = fminf(a * SCALE, XPCLAMP);  // upper clamp off the scan path
        }
        int b = r >> 11, t = r & 2047;
#pragma unroll
        for (int q = 0; q < 4; ++q) {
            *(float2*)(xpT + ((size_t)(b * 4 + q) * Tz + t) * 2) =
                make_float2(res[2 * q], res[2 * q + 1]);
        }
    }
    if (r < Bz) out_tail[r] = (float)lengths[r];
    if (prog != nullptr && r < 64) prog[r] = 0;  // 4 flags, 64B-line padded
}

// ---------------------------------------------------------------------------
// Scan core: h = tanh(xp_t + W_hh h), 4 lanes/batch, lane q holds h[2q],h[2q+1].
// Cross-lane h all-gather via DPP quad_perm. Dot tree-reduced (~16cy chain).
// hs is T-MAJOR hs[t][b][8]: 512 contiguous B per wave per step, PLAIN cached
// stores (full rate into the producer XCD's write-back L2).
// PUB=true: every 256 steps each wave publishes prog[wv*16] with an
// __ATOMIC_RELEASE agent store — the compiler emits s_waitcnt vmcnt(0) +
// buffer_wbl2 (L2->L3 writeback) + flag store, so the wave's chunk data is
// L3-visible strictly before the flag. Consumers read hs with agent-scope
// (L2-bypassing) loads, so L3 currency is sufficient.
// ---------------------------------------------------------------------------
#define QROT(x, CTRL) \
    __int_as_float(__builtin_amdgcn_update_dpp(0, __float_as_int(x), (CTRL), 0xF, 0xF, true))
// quad_perm ctrl: rot1=[1,2,3,0]=0x39, rot2=[2,3,0,1]=0x4E, rot3=[3,0,1,2]=0x93

__device__ __forceinline__ float fast_tanh_pre(float m) {
    // m = 2*a/ln2 already; bounded < 126 by the xproj clamp (+h headroom).
    // tanh(a) = (e-1)/(e+1), e = 2^m; exp2(-big)->0 gives -1 exactly.
#if __has_builtin(__builtin_amdgcn_exp2f)
    float e = __builtin_amdgcn_exp2f(m);
#else
    float e = exp2f(m);
#endif
#if __has_builtin(__builtin_amdgcn_rcpf)
    return (e - 1.0f) * __builtin_amdgcn_rcpf(e + 1.0f);
#else
    return (e - 1.0f) / (e + 1.0f);
#endif
}

#define STEP(xx, yy, toff) do { \
    float p1x = QROT(h0, 0x39), p1y = QROT(h1, 0x39); \
    float p2x = QROT(h0, 0x4E), p2y = QROT(h1, 0x4E); \
    float p3x = QROT(h0, 0x93), p3y = QROT(h1, 0x93); \
    float s0a = fmaf(h1, w0[1], fmaf(h0, w0[0], (xx))); \
    float s0b = fmaf(h1, w1[1], fmaf(h0, w1[0], (yy))); \
    float s1a = fmaf(p1y, w0[3], p1x * w0[2]); \
    float s1b = fmaf(p1y, w1[3], p1x * w1[2]); \
    float s2a = fmaf(p2y, w0[5], p2x * w0[4]); \
    float s2b = fmaf(p2y, w1[5], p2x * w1[4]); \
    float s3a = fmaf(p3y, w0[7], p3x * w0[6]); \
    float s3b = fmaf(p3y, w1[7], p3x * w1[6]); \
    h0 = fast_tanh_pre((s0a + s1a) + (s2a + s3a)); \
    h1 = fast_tanh_pre((s0b + s1b) + (s2b + s3b)); \
    *(float2*)(hs_base + (size_t)(toff) * (Bz * Hz)) = make_float2(h0, h1); \
} while (0)

template <bool PUB>
__device__ __forceinline__ void scan_run(
    const float* __restrict__ xpT, const float* __restrict__ W_hh,
    float* __restrict__ hs, int b, int q, int* prog, int wv)
{
    int i0 = 2 * q, i1 = 2 * q + 1;
    // Weights in quad-rotation order: term r uses h-pair from lane (q+r)&3.
    float w0[8], w1[8];
#pragma unroll
    for (int r = 0; r < 4; ++r) {
        int jj = ((q + r) & 3) * 2;
        w0[2 * r]     = W_hh[i0 * 8 + jj]     * SCALE;
        w0[2 * r + 1] = W_hh[i0 * 8 + jj + 1] * SCALE;
        w1[2 * r]     = W_hh[i1 * 8 + jj]     * SCALE;
        w1[2 * r + 1] = W_hh[i1 * 8 + jj + 1] * SCALE;
    }

    const float4* xp4 = (const float4*)(xpT + (size_t)(b * 4 + q) * Tz * 2);
    float* hs_base = hs + (size_t)b * Hz + 2 * q;   // t-major: + t*(Bz*Hz)

    float h0 = 0.0f, h1 = 0.0f;
    // prefetch depth 2 (cover ~500cy L3 latency; 8 steps of compute in between)
    float4 A0 = xp4[0], A1 = xp4[1], A2 = xp4[2], A3 = xp4[3];
    float4 B0 = xp4[4], B1 = xp4[5], B2 = xp4[6], B3 = xp4[7];

    for (int c = 0; c < Tz / 8; ++c) {
        // reads up to 128B past the lane stream on the last iters -> lands in
        // the next lane's stream / start of hs region. Allocated; harmless.
        float4 C0 = xp4[4 * c + 8],  C1 = xp4[4 * c + 9];
        float4 C2 = xp4[4 * c + 10], C3 = xp4[4 * c + 11];
        int t0 = c * 8;
        STEP(A0.x, A0.y, t0 + 0); STEP(A0.z, A0.w, t0 + 1);
        STEP(A1.x, A1.y, t0 + 2); STEP(A1.z, A1.w, t0 + 3);
        STEP(A2.x, A2.y, t0 + 4); STEP(A2.z, A2.w, t0 + 5);
        STEP(A3.x, A3.y, t0 + 6); STEP(A3.z, A3.w, t0 + 7);
        A0 = B0; A1 = B1; A2 = B2; A3 = B3;
        B0 = C0; B1 = C1; B2 = C2; B3 = C3;
        if (PUB && ((c & 31) == 31)) {
            // per-wave RELEASE publish: waitcnt + L2 writeback + flag store.
            if ((threadIdx.x & 63) == 0)
                __hip_atomic_store(&prog[wv * 16], (c >> 5) + 1,
                                   __ATOMIC_RELEASE, __HIP_MEMORY_SCOPE_AGENT);
        }
    }
}

// Fallback standalone scan (plain stores; kernel boundary is the release).
__global__ __launch_bounds__(64) void k_scan(
    const float* __restrict__ xpT, const float* __restrict__ W_hh,
    float* __restrict__ hs)
{
    int lane = threadIdx.x;
    scan_run<false>(xpT, W_hh, hs, blockIdx.x * 16 + (lane >> 2), lane & 3,
                    nullptr, 0);
}

// ---------------------------------------------------------------------------
// Fused producer/consumer kernel. 256 blocks (<= #CUs -> all co-resident).
// Block 0: 4 scan waves (16 batches each), publish prog[wv*16] per 256-step
// chunk (RELEASE -> data in L3 before flag). Blocks 1..255: tile = one
// t-value x 64 batches (2KB hs stage via agent-scope loads = L3-fresh,
// 256KB logits store). Block k handles t = k-1, k-1+255, ... so each chunk's
// 256 tiles land on all 255 blocks -> chunk drain (~10us at full BW) matches
// chunk production cadence.
// ---------------------------------------------------------------------------
__global__ __launch_bounds__(256) void k_fused(
    const float* __restrict__ xpT, const float* __restrict__ W_hh,
    float* __restrict__ hs, const int* __restrict__ lengths,
    const float* __restrict__ W_out, const float* __restrict__ b_out,
    float* __restrict__ out, int* __restrict__ prog)
{
    __shared__ float4 sh4[128];  // 64 rows x 8 floats
    int tid = threadIdx.x;

    if (blockIdx.x == 0) {  // producer
        __builtin_amdgcn_s_setprio(3);  // win issue ties if a consumer co-resides
        int lane = tid & 63, wv = tid >> 6;
        scan_run<true>(xpT, W_hh, hs, wv * 16 + (lane >> 2), lane & 3, prog, wv);
        return;
    }

    // consumer: hoist W_out rows + bias into registers
    float w[4][8], bo[4];
    if (tid < Oz / 4) {
#pragma unroll
        for (int k = 0; k < 4; ++k) {
            const float4* wr = (const float4*)(W_out + (size_t)(tid * 4 + k) * 8);
            float4 wa = wr[0], wb = wr[1];
            w[k][0] = wa.x; w[k][1] = wa.y; w[k][2] = wa.z; w[k][3] = wa.w;
            w[k][4] = wb.x; w[k][5] = wb.y; w[k][6] = wb.z; w[k][7] = wb.w;
            bo[k] = b_out[tid * 4 + k];
        }
    }

    for (int t = (int)blockIdx.x - 1; t < Tz; t += 255) {
        int need = (t >> 8) + 1;  // chunk index + 1
        if (tid == 0) {
            for (;;) {
                int m0 = __hip_atomic_load(&prog[0], __ATOMIC_RELAXED,
                                           __HIP_MEMORY_SCOPE_AGENT);
                int m1 = __hip_atomic_load(&prog[16], __ATOMIC_RELAXED,
                                           __HIP_MEMORY_SCOPE_AGENT);
                int m2 = __hip_atomic_load(&prog[32], __ATOMIC_RELAXED,
                                           __HIP_MEMORY_SCOPE_AGENT);
                int m3 = __hip_atomic_load(&prog[48], __ATOMIC_RELAXED,
                                           __HIP_MEMORY_SCOPE_AGENT);
                int mn = min(min(m0, m1), min(m2, m3));
                if (mn >= need) break;
                __builtin_amdgcn_s_sleep(16);
            }
        }
        __syncthreads();  // flag observed; barrier orders the hs loads below

        {   // stage 2KB contiguous: 256 threads x 8B (agent loads: L3-fresh)
            uint64_t u = __hip_atomic_load(
                (const uint64_t*)hs + (size_t)t * 256 + tid,
                __ATOMIC_RELAXED, __HIP_MEMORY_SCOPE_AGENT);
            float2 v;
            __builtin_memcpy(&v, &u, 8);
            int b = tid >> 2;  // 4 threads per batch row
            if (t >= lengths[b]) v = make_float2(0.f, 0.f);
            ((float2*)sh4)[tid] = v;
        }
        __syncthreads();

        if (tid < Oz / 4) {  // 250 active threads
            for (int rr = 0; rr < 64; ++rr) {  // rr = batch
                float4 ha = sh4[rr * 2], hb = sh4[rr * 2 + 1];  // LDS broadcast
                float r[4];
#pragma unroll
                for (int k = 0; k < 4; ++k) {
                    float a = bo[k];
                    a = fmaf(ha.x, w[k][0], a); a = fmaf(ha.y, w[k][1], a);
                    a = fmaf(ha.z, w[k][2], a); a = fmaf(ha.w, w[k][3], a);
                    a = fmaf(hb.x, w[k][4], a); a = fmaf(hb.y, w[k][5], a);
                    a = fmaf(hb.z, w[k][6], a); a = fmaf(hb.w, w[k][7], a);
                    r[k] = a;
                }
                f32x4 acc = { r[0], r[1], r[2], r[3] };
                // plain (cached) store: full-line streaming through L2
                *((f32x4*)(out + ((size_t)rr * Tz + t) * Oz) + tid) = acc;
            }
        }
        __syncthreads();  // LDS reused next tile
    }
}

// ---------------------------------------------------------------------------
// Fallback output projection (3-kernel path), t-major hs, 2t x 64b tiles.
// ---------------------------------------------------------------------------
__global__ __launch_bounds__(256) void k_out(
    const float* __restrict__ hs, const int* __restrict__ lengths,
    const float* __restrict__ W_out, const float* __restrict__ b_out,
    float* __restrict__ out)
{
    __shared__ float4 sh4[256];  // 128 rows x 8 floats; row rr = tt*64 + b
    int tid = threadIdx.x;
    int t0 = blockIdx.x * 2;

    {
        float4 v = ((const float4*)hs)[(size_t)t0 * 128 + tid];
        int tt = tid >> 7, b = (tid & 127) >> 1;
        if (t0 + tt >= lengths[b]) v = make_float4(0.f, 0.f, 0.f, 0.f);
        sh4[tid] = v;
    }
    __syncthreads();

    if (tid >= Oz / 4) return;

    float w[4][8];
    float bo[4];
#pragma unroll
    for (int k = 0; k < 4; ++k) {
        const float4* wr = (const float4*)(W_out + (size_t)(tid * 4 + k) * 8);
        float4 wa = wr[0], wb = wr[1];
        w[k][0] = wa.x; w[k][1] = wa.y; w[k][2] = wa.z; w[k][3] = wa.w;
        w[k][4] = wb.x; w[k][5] = wb.y; w[k][6] = wb.z; w[k][7] = wb.w;
        bo[k] = b_out[tid * 4 + k];
    }

    for (int rr = 0; rr < 128; ++rr) {
        float4 ha = sh4[rr * 2], hb = sh4[rr * 2 + 1];
        int tt = rr >> 6, b = rr & 63;
        float r[4];
#pragma unroll
        for (int k = 0; k < 4; ++k) {
            float a = bo[k];
            a = fmaf(ha.x, w[k][0], a); a = fmaf(ha.y, w[k][1], a);
            a = fmaf(ha.z, w[k][2], a); a = fmaf(ha.w, w[k][3], a);
            a = fmaf(hb.x, w[k][4], a); a = fmaf(hb.y, w[k][5], a);
            a = fmaf(hb.z, w[k][6], a); a = fmaf(hb.w, w[k][7], a);
            r[k] = a;
        }
        f32x4 acc = { r[0], r[1], r[2], r[3] };
        *((f32x4*)(out + ((size_t)b * Tz + t0 + tt) * Oz) + tid) = acc;
    }
}

// ---------------------------------------------------------------------------
extern "C" void kernel_launch(void* const* d_in, const int* in_sizes, int n_in,
                              void* d_out, int out_size, void* d_ws, size_t ws_size,
                              hipStream_t stream)
{
    const int*   X       = (const int*)d_in[0];
    const int*   lengths = (const int*)d_in[1];
    const float* emb     = (const float*)d_in[2];
    const float* W_ih    = (const float*)d_in[3];
    const float* W_hh    = (const float*)d_in[4];
    const float* b_ih    = (const float*)d_in[5];
    const float* b_hh    = (const float*)d_in[6];
    const float* W_out   = (const float*)d_in[7];
    const float* b_out   = (const float*)d_in[8];

    float* out   = (float*)d_out;
    float* xpT   = (float*)d_ws;                     // 4 MB (lane-major x_proj)
    float* hs    = xpT + (size_t)Bz * Tz * Hz;       // 4 MB (t-major hidden states)

    // lengths tail of d_out (output 1 of the tuple)
    float* out_tail = out + (size_t)Bz * Tz * Oz;

    size_t base = (size_t)Bz * Tz * Hz * 4 * 2;      // 8 MB (xpT + hs)
    bool fused = (ws_size >= base + 256);
    int* prog = fused ? (int*)((char*)d_ws + base) : nullptr;

    k_xproj<<<(Bz * Tz + 255) / 256, 256, 0, stream>>>(X, lengths, emb, W_ih,
                                                       b_ih, b_hh, xpT, out_tail,
                                                       prog);
    if (fused) {
        k_fused<<<256, 256, 0, stream>>>(xpT, W_hh, hs, lengths, W_out, b_out,
                                         out, prog);
    } else {
        k_scan<<<Bz / 16, 64, 0, stream>>>(xpT, W_hh, hs);
        k_out<<<Tz / 2, 256, 0, stream>>>(hs, lengths, W_out, b_out, out);
    }
}

// Round 5
// 650.195 us; speedup vs baseline: 1.1700x; 1.1400x over previous
//
#include <hip/hip_runtime.h>
#include <cstdint>
#include <cstddef>
#include <cstring>

// Problem dims (RNN_57208964382771)
#define Bz 64
#define Tz 2048
#define Hz 8
#define Vz 1000
#define Oz 1000

// 2/ln2 — folded into W_hh and x_proj so fast_tanh skips its input scaling mul
#define SCALE 2.885390081777927f
// xp clamp: 126 - 8*0.354*SCALE (max |h|-contribution) ~= 117.8 -> 117
#define XPCLAMP 117.0f

typedef float f32x4 __attribute__((ext_vector_type(4)));

// Layouts:
//   xpJ[b][j][t]  (j = h index 0..7; t contiguous per (b,j) lane stream)
//   hs[t][b][j]   (t-major; 512 floats per t; wave writes 256B contiguous)

// ---------------------------------------------------------------------------
// Kernel 1: xpJ[b][j][t] = min((dot(emb[X[b,t]], W_ih[j,:]) + b_ih + b_hh)
//           * SCALE, XPCLAMP). Also writes lengths tail of d_out and zeroes
//           the padded progress flags (stream order makes them visible).
// Each wave = one b, 64 consecutive t -> each of the 8 stores is 256B
// contiguous per wave.
// ---------------------------------------------------------------------------
__global__ __launch_bounds__(256) void k_xproj(
    const int* __restrict__ X, const int* __restrict__ lengths,
    const float* __restrict__ emb, const float* __restrict__ W_ih,
    const float* __restrict__ b_ih, const float* __restrict__ b_hh,
    float* __restrict__ xpJ, float* __restrict__ out_tail,
    int* __restrict__ prog)
{
    int r = blockIdx.x * 256 + threadIdx.x;
    if (r < Bz * Tz) {
        int v = X[r];
        const float4* e4 = (const float4*)(emb + (size_t)v * Hz);
        float4 ea = e4[0], eb = e4[1];
        int b = r >> 11, t = r & 2047;
#pragma unroll
        for (int i = 0; i < 8; ++i) {
            const float* w = W_ih + i * 8;  // uniform address -> scalar loads
            float a = b_ih[i] + b_hh[i];
            a = fmaf(ea.x, w[0], a); a = fmaf(ea.y, w[1], a);
            a = fmaf(ea.z, w[2], a); a = fmaf(ea.w, w[3], a);
            a = fmaf(eb.x, w[4], a); a = fmaf(eb.y, w[5], a);
            a = fmaf(eb.z, w[6], a); a = fmaf(eb.w, w[7], a);
            xpJ[((size_t)(b * 8 + i)) * Tz + t] = fminf(a * SCALE, XPCLAMP);
        }
    }
    if (r < Bz) out_tail[r] = (float)lengths[r];
    if (prog != nullptr && r < 128) prog[r] = 0;  // 8 flags, 64B-line padded
}

// ---------------------------------------------------------------------------
// Scan: h = tanh(xp_t + W_hh h). ONE h per lane: lane l -> batch (blk*8 +
// (l>>3)), h-index i = l&7. All-gather of the 8 h values via XOR-mask DPP:
//   XOR1/2/3 within quads: quad_perm 0xB1 / 0x4E / 0x1B
//   XOR7: row_half_mirror (0x141);  XOR4/5/6: quad_perm of the mirror.
// Weight w[r] pairs the XOR-r gathered value: w[r] = W_hh[i][i^r] * SCALE.
// Per-step: 7 DPP + 8 fma/mul + 3 add + exp2 + rcp + 1 scalar store
// (~62 cyc issue, ~64 cyc dep chain for a single wave).
// One wave per block -> each producer wave owns a full CU (no SIMD sharing).
// ---------------------------------------------------------------------------
#define QROT(x, CTRL) \
    __int_as_float(__builtin_amdgcn_update_dpp(0, __float_as_int(x), (CTRL), 0xF, 0xF, true))
// quad_perm XOR1=0xB1, XOR2=0x4E, XOR3=0x1B; row_half_mirror=0x141

__device__ __forceinline__ float fast_tanh_pre(float m) {
    // m = 2*a/ln2 already; bounded < 126 by the xproj clamp (+h headroom).
    // tanh(a) = (e-1)/(e+1), e = 2^m; exp2(-big)->0 gives -1 exactly.
#if __has_builtin(__builtin_amdgcn_exp2f)
    float e = __builtin_amdgcn_exp2f(m);
#else
    float e = exp2f(m);
#endif
#if __has_builtin(__builtin_amdgcn_rcpf)
    return (e - 1.0f) * __builtin_amdgcn_rcpf(e + 1.0f);
#else
    return (e - 1.0f) / (e + 1.0f);
#endif
}

#define STEP(xx, toff) do { \
    float g1 = QROT(h, 0xB1); \
    float g2 = QROT(h, 0x4E); \
    float g3 = QROT(h, 0x1B); \
    float m7 = QROT(h, 0x141); \
    float g6 = QROT(m7, 0xB1); \
    float g5 = QROT(m7, 0x4E); \
    float g4 = QROT(m7, 0x1B); \
    float p0 = fmaf(g1, w[1], fmaf(h, w[0], (xx))); \
    float p1 = fmaf(g3, w[3], g2 * w[2]); \
    float p2 = fmaf(g5, w[5], g4 * w[4]); \
    float p3 = fmaf(m7, w[7], g6 * w[6]); \
    h = fast_tanh_pre((p0 + p1) + (p2 + p3)); \
    hsp[(size_t)(toff) * (Bz * Hz)] = h; \
} while (0)

template <bool PUB>
__device__ __forceinline__ void scan_run(
    const float* __restrict__ xpJ, const float* __restrict__ W_hh,
    float* __restrict__ hs, int lane, int blk, int* prog)
{
    int bb = blk * 8 + (lane >> 3);  // batch
    int i = lane & 7;                // h index this lane owns

    float w[8];
#pragma unroll
    for (int r = 0; r < 8; ++r)
        w[r] = W_hh[i * 8 + (i ^ r)] * SCALE;

    const float4* xp4 = (const float4*)(xpJ + ((size_t)bb * 8 + i) * Tz);
    float* hsp = hs + (size_t)bb * Hz + i;  // t-major: + t*(Bz*Hz)

    float h = 0.0f;
    // prefetch depth 2 (2 float4 per 8-step iter; 16 steps ~ 1000cy in flight)
    float4 A0 = xp4[0], A1 = xp4[1];
    float4 B0 = xp4[2], B1 = xp4[3];

    for (int c = 0; c < Tz / 8; ++c) {
        // reads up to 32B past the lane stream on the last iters -> lands in
        // the next lane's stream / start of hs region. Allocated; harmless.
        float4 C0 = xp4[2 * c + 4], C1 = xp4[2 * c + 5];
        int t0 = c * 8;
        STEP(A0.x, t0 + 0); STEP(A0.y, t0 + 1);
        STEP(A0.z, t0 + 2); STEP(A0.w, t0 + 3);
        STEP(A1.x, t0 + 4); STEP(A1.y, t0 + 5);
        STEP(A1.z, t0 + 6); STEP(A1.w, t0 + 7);
        A0 = B0; A1 = B1; B0 = C0; B1 = C1;
        if (PUB && ((c & 31) == 31)) {
            // per-wave RELEASE publish (vmcnt drain + L2 writeback + flag):
            // chunk of 256 steps for batches blk*8..blk*8+7 is L3-visible.
            if (lane == 0)
                __hip_atomic_store(&prog[blk * 16], (c >> 5) + 1,
                                   __ATOMIC_RELEASE, __HIP_MEMORY_SCOPE_AGENT);
        }
    }
}

// Fallback standalone scan (plain stores; kernel boundary is the release).
__global__ __launch_bounds__(64) void k_scan(
    const float* __restrict__ xpJ, const float* __restrict__ W_hh,
    float* __restrict__ hs)
{
    scan_run<false>(xpJ, W_hh, hs, threadIdx.x, blockIdx.x, nullptr);
}

// ---------------------------------------------------------------------------
// Fused producer/consumer kernel. 256 blocks (<= #CUs -> all co-resident).
// Blocks 0..7: ONE producer wave each (8 batches; tid>=64 exits immediately),
// publish prog[blk*16] per 256-step chunk with RELEASE.
// Blocks 8..255: tile = one t x 64 batches (2KB agent-scope hs stage ->
// L3-fresh, 256KB logits store). Block k handles t = k-8, k-8+248, ...
// ---------------------------------------------------------------------------
__global__ __launch_bounds__(256) void k_fused(
    const float* __restrict__ xpJ, const float* __restrict__ W_hh,
    float* __restrict__ hs, const int* __restrict__ lengths,
    const float* __restrict__ W_out, const float* __restrict__ b_out,
    float* __restrict__ out, int* __restrict__ prog)
{
    __shared__ float4 sh4[128];  // 64 rows x 8 floats
    int tid = threadIdx.x;

    if (blockIdx.x < 8) {  // producer block: one wave, own CU
        if (tid < 64) {
            __builtin_amdgcn_s_setprio(3);
            scan_run<true>(xpJ, W_hh, hs, tid, (int)blockIdx.x, prog);
        }
        return;
    }

    // consumer: hoist W_out rows + bias into registers
    float w[4][8], bo[4];
    if (tid < Oz / 4) {
#pragma unroll
        for (int k = 0; k < 4; ++k) {
            const float4* wr = (const float4*)(W_out + (size_t)(tid * 4 + k) * 8);
            float4 wa = wr[0], wb = wr[1];
            w[k][0] = wa.x; w[k][1] = wa.y; w[k][2] = wa.z; w[k][3] = wa.w;
            w[k][4] = wb.x; w[k][5] = wb.y; w[k][6] = wb.z; w[k][7] = wb.w;
            bo[k] = b_out[tid * 4 + k];
        }
    }

    for (int t = (int)blockIdx.x - 8; t < Tz; t += 248) {
        int need = (t >> 8) + 1;  // chunk index + 1
        if (tid == 0) {
            for (;;) {
                int mn = 0x7fffffff;
#pragma unroll
                for (int p = 0; p < 8; ++p) {
                    int m = __hip_atomic_load(&prog[p * 16], __ATOMIC_RELAXED,
                                              __HIP_MEMORY_SCOPE_AGENT);
                    mn = min(mn, m);
                }
                if (mn >= need) break;
                __builtin_amdgcn_s_sleep(16);
            }
        }
        __syncthreads();  // flag observed; barrier orders the hs loads below

        {   // stage 2KB contiguous: 256 threads x 8B (agent loads: L3-fresh)
            uint64_t u = __hip_atomic_load(
                (const uint64_t*)hs + (size_t)t * 256 + tid,
                __ATOMIC_RELAXED, __HIP_MEMORY_SCOPE_AGENT);
            float2 v;
            __builtin_memcpy(&v, &u, 8);
            int b = tid >> 2;  // 4 threads per batch row
            if (t >= lengths[b]) v = make_float2(0.f, 0.f);
            ((float2*)sh4)[tid] = v;
        }
        __syncthreads();

        if (tid < Oz / 4) {  // 250 active threads
            for (int rr = 0; rr < 64; ++rr) {  // rr = batch
                float4 ha = sh4[rr * 2], hb = sh4[rr * 2 + 1];  // LDS broadcast
                float r[4];
#pragma unroll
                for (int k = 0; k < 4; ++k) {
                    float a = bo[k];
                    a = fmaf(ha.x, w[k][0], a); a = fmaf(ha.y, w[k][1], a);
                    a = fmaf(ha.z, w[k][2], a); a = fmaf(ha.w, w[k][3], a);
                    a = fmaf(hb.x, w[k][4], a); a = fmaf(hb.y, w[k][5], a);
                    a = fmaf(hb.z, w[k][6], a); a = fmaf(hb.w, w[k][7], a);
                    r[k] = a;
                }
                f32x4 acc = { r[0], r[1], r[2], r[3] };
                // plain (cached) store: full-line streaming through L2
                *((f32x4*)(out + ((size_t)rr * Tz + t) * Oz) + tid) = acc;
            }
        }
        __syncthreads();  // LDS reused next tile
    }
}

// ---------------------------------------------------------------------------
// Fallback output projection (3-kernel path), t-major hs, 2t x 64b tiles.
// ---------------------------------------------------------------------------
__global__ __launch_bounds__(256) void k_out(
    const float* __restrict__ hs, const int* __restrict__ lengths,
    const float* __restrict__ W_out, const float* __restrict__ b_out,
    float* __restrict__ out)
{
    __shared__ float4 sh4[256];  // 128 rows x 8 floats; row rr = tt*64 + b
    int tid = threadIdx.x;
    int t0 = blockIdx.x * 2;

    {
        float4 v = ((const float4*)hs)[(size_t)t0 * 128 + tid];
        int tt = tid >> 7, b = (tid & 127) >> 1;
        if (t0 + tt >= lengths[b]) v = make_float4(0.f, 0.f, 0.f, 0.f);
        sh4[tid] = v;
    }
    __syncthreads();

    if (tid >= Oz / 4) return;

    float w[4][8];
    float bo[4];
#pragma unroll
    for (int k = 0; k < 4; ++k) {
        const float4* wr = (const float4*)(W_out + (size_t)(tid * 4 + k) * 8);
        float4 wa = wr[0], wb = wr[1];
        w[k][0] = wa.x; w[k][1] = wa.y; w[k][2] = wa.z; w[k][3] = wa.w;
        w[k][4] = wb.x; w[k][5] = wb.y; w[k][6] = wb.z; w[k][7] = wb.w;
        bo[k] = b_out[tid * 4 + k];
    }

    for (int rr = 0; rr < 128; ++rr) {
        float4 ha = sh4[rr * 2], hb = sh4[rr * 2 + 1];
        int tt = rr >> 6, b = rr & 63;
        float r[4];
#pragma unroll
        for (int k = 0; k < 4; ++k) {
            float a = bo[k];
            a = fmaf(ha.x, w[k][0], a); a = fmaf(ha.y, w[k][1], a);
            a = fmaf(ha.z, w[k][2], a); a = fmaf(ha.w, w[k][3], a);
            a = fmaf(hb.x, w[k][4], a); a = fmaf(hb.y, w[k][5], a);
            a = fmaf(hb.z, w[k][6], a); a = fmaf(hb.w, w[k][7], a);
            r[k] = a;
        }
        f32x4 acc = { r[0], r[1], r[2], r[3] };
        *((f32x4*)(out + ((size_t)b * Tz + t0 + tt) * Oz) + tid) = acc;
    }
}

// ---------------------------------------------------------------------------
extern "C" void kernel_launch(void* const* d_in, const int* in_sizes, int n_in,
                              void* d_out, int out_size, void* d_ws, size_t ws_size,
                              hipStream_t stream)
{
    const int*   X       = (const int*)d_in[0];
    const int*   lengths = (const int*)d_in[1];
    const float* emb     = (const float*)d_in[2];
    const float* W_ih    = (const float*)d_in[3];
    const float* W_hh    = (const float*)d_in[4];
    const float* b_ih    = (const float*)d_in[5];
    const float* b_hh    = (const float*)d_in[6];
    const float* W_out   = (const float*)d_in[7];
    const float* b_out   = (const float*)d_in[8];

    float* out   = (float*)d_out;
    float* xpJ   = (float*)d_ws;                     // 4 MB (per-lane t-streams)
    float* hs    = xpJ + (size_t)Bz * Tz * Hz;       // 4 MB (t-major hidden states)

    // lengths tail of d_out (output 1 of the tuple)
    float* out_tail = out + (size_t)Bz * Tz * Oz;

    size_t base = (size_t)Bz * Tz * Hz * 4 * 2;      // 8 MB (xpJ + hs)
    bool fused = (ws_size >= base + 512);
    int* prog = fused ? (int*)((char*)d_ws + base) : nullptr;

    k_xproj<<<(Bz * Tz + 255) / 256, 256, 0, stream>>>(X, lengths, emb, W_ih,
                                                       b_ih, b_hh, xpJ, out_tail,
                                                       prog);
    if (fused) {
        k_fused<<<256, 256, 0, stream>>>(xpJ, W_hh, hs, lengths, W_out, b_out,
                                         out, prog);
    } else {
        k_scan<<<Bz / 8, 64, 0, stream>>>(xpJ, W_hh, hs);
        k_out<<<Tz / 2, 256, 0, stream>>>(hs, lengths, W_out, b_out, out);
    }
}